// Round 2
// baseline (547.759 us; speedup 1.0000x reference)
//
#include <hip/hip_runtime.h>

// NNMF fused: B=8192, NIN=3072, NOUT=512, 5 iterations.
// R8: single-barrier pipelined slot.
//  R7 rocprof: slot = 6560 cy but MFMA only 2048 cy (MfmaUtil 29%), VALU 1500,
//  loads ~2400 pipelined -> residual ~3000 cy is phase serialization: the
//  A->rcp->r8write and B phases each sit between barriers (2/slot, 48/iter)
//  with only 2 barrier-locked waves/SIMD to hide drain.
//  Fix: double-buffer r8_lds and x_lds; slot s does {B(s) | A(s+1) | r(s+1) |
//  W2[s+1]/W1[s+2]/x[s+3] loads} in ONE barrier-free region, 1 barrier/slot
//  (25/iter). A is register-only (hfr/w1buf) so it interleaves with B's
//  ds_reads+MFMAs; the rcp tail hides under 64 MFMAs of issue.
//  Numerics unchanged from R7 (fp8 both phases, exact-it0 d0inv, fp32 h master).

#define NIN 3072
#define NOUT 512

using f32x4  = __attribute__((ext_vector_type(4))) float;

__device__ __forceinline__ unsigned short f2bf(float f) {
    unsigned int u = __builtin_bit_cast(unsigned int, f);
    return (unsigned short)((u + 0x7fffu + ((u >> 16) & 1u)) >> 16);  // RNE
}
__device__ __forceinline__ float bf2f(unsigned short s) {
    unsigned int u = ((unsigned int)s) << 16;
    return __builtin_bit_cast(float, u);
}

// LDS-only barrier: cross-wave deps in the slot loop are LDS-only; global
// prefetches stay in flight (consumed by issuing wave, compiler inserts vmcnt).
#define LDS_BARRIER() do {                                   \
    asm volatile("s_waitcnt lgkmcnt(0)" ::: "memory");       \
    __builtin_amdgcn_s_barrier();                            \
    asm volatile("" ::: "memory");                           \
} while (0)

// ---------------------------------------------------------------------------
// prep_w: W (fp32 [512][3072]) ->
//   W2 (fp8 e4m3, x4096, pair-packed for Phase B):
//     byte addr = ((kcg*16 + pr)*64 + l)*16 + h8*8 + j
//     element: n = (pr*2+h8)*16 + (l&15), k = kcg*32 + (l>>4)*8 + j
//   W1 (fp8 e4m3, x4096, Phase A B-frags):
//     W1[((ktg*16+nc)*64 + l)*8 + j] = fp8(W[nc*32+(l>>4)*8+j][ktg*16+(l&15)]*4096)
// ---------------------------------------------------------------------------
__global__ void prep_w(const float* __restrict__ W,
                       unsigned char* __restrict__ W1,
                       unsigned char* __restrict__ W2) {
    int t = blockIdx.x * 256 + threadIdx.x;   // 0 .. 294911
    if (t < 98304) {
        int f = t >> 6, l = t & 63;
        int kcg = f >> 4, pr = f & 15;
        int kbase = kcg * 32 + ((l >> 4) << 3);
        unsigned int words[4];
        #pragma unroll
        for (int h8 = 0; h8 < 2; ++h8) {
            int n = (pr * 2 + h8) * 16 + (l & 15);
            const float* src = W + (size_t)n * NIN + kbase;
            float v[8];
            #pragma unroll
            for (int j = 0; j < 8; ++j) v[j] = src[j] * 4096.0f;
            int lo32 = __builtin_amdgcn_cvt_pk_fp8_f32(v[0], v[1], 0, false);
            lo32     = __builtin_amdgcn_cvt_pk_fp8_f32(v[2], v[3], lo32, true);
            int hi32 = __builtin_amdgcn_cvt_pk_fp8_f32(v[4], v[5], 0, false);
            hi32     = __builtin_amdgcn_cvt_pk_fp8_f32(v[6], v[7], hi32, true);
            words[h8 * 2]     = (unsigned int)lo32;
            words[h8 * 2 + 1] = (unsigned int)hi32;
        }
        *reinterpret_cast<uint4*>(W2 + (size_t)t * 16) =
            *reinterpret_cast<uint4*>(words);
    } else {
        int u = t - 98304;                    // 0 .. 196607
        int f = u >> 6, l = u & 63;
        int ktg = f >> 4, nc = f & 15;
        int k = ktg * 16 + (l & 15);
        int nb = nc * 32 + ((l >> 4) << 3);
        float v[8];
        #pragma unroll
        for (int j = 0; j < 8; ++j) v[j] = W[(size_t)(nb + j) * NIN + k] * 4096.0f;
        int lo32 = __builtin_amdgcn_cvt_pk_fp8_f32(v[0], v[1], 0, false);
        lo32     = __builtin_amdgcn_cvt_pk_fp8_f32(v[2], v[3], lo32, true);
        int hi32 = __builtin_amdgcn_cvt_pk_fp8_f32(v[4], v[5], 0, false);
        hi32     = __builtin_amdgcn_cvt_pk_fp8_f32(v[6], v[7], hi32, true);
        uint2 o; o.x = (unsigned int)lo32; o.y = (unsigned int)hi32;
        *reinterpret_cast<uint2*>(W1 + (size_t)u * 8) = o;
    }
}

// ---------------------------------------------------------------------------
// prep_cs: d0inv[k] = 1 / (sum_n h_init[n]*W[n][k] + 1e-20)  (it0 denom, exact fp32)
// ---------------------------------------------------------------------------
__global__ void prep_cs(const float* __restrict__ W, const float* __restrict__ h_init,
                        float* __restrict__ d0inv) {
    int k = blockIdx.x * 256 + threadIdx.x;   // 0..3071
    float s = 0.f;
    for (int n = 0; n < NOUT; ++n) s += h_init[n] * W[(size_t)n * NIN + k];
    d0inv[k] = 1.0f / (s + 1e-20f);
}

// ---------------------------------------------------------------------------
// prep_x: per-row normalize x and store bf16 (coalesced, R3-verified).
// ---------------------------------------------------------------------------
__global__ void prep_x(const float* __restrict__ x, unsigned short* __restrict__ X2) {
    int b = blockIdx.x;
    int t = threadIdx.x;                      // 256 threads
    const float4* r4 = reinterpret_cast<const float4*>(x + (size_t)b * NIN);
    float s = 0.f;
    float4 v0 = r4[t], v1 = r4[t + 256], v2 = r4[t + 512];
    s = v0.x + v0.y + v0.z + v0.w + v1.x + v1.y + v1.z + v1.w + v2.x + v2.y + v2.z + v2.w;
    #pragma unroll
    for (int off = 32; off > 0; off >>= 1) s += __shfl_down(s, off, 64);
    __shared__ float wsum[4];
    int w = t >> 6, l = t & 63;
    if (l == 0) wsum[w] = s;
    __syncthreads();
    float inv = 1.0f / (wsum[0] + wsum[1] + wsum[2] + wsum[3] + 1e-20f);
    unsigned short* orow = X2 + (size_t)b * NIN;
    #pragma unroll
    for (int c = 0; c < 3; ++c) {
        float4 v = (c == 0) ? v0 : (c == 1) ? v1 : v2;
        ushort4 o;
        o.x = f2bf(v.x * inv); o.y = f2bf(v.y * inv);
        o.z = f2bf(v.z * inv); o.w = f2bf(v.w * inv);
        *reinterpret_cast<ushort4*>(orow + (t + c * 256) * 4) = o;
    }
}

// ---------------------------------------------------------------------------
// Main kernel. 256 blocks x 512 threads (8 waves), 32 rows/block, 1 block/CU.
// Pipelined single-barrier slots; fp8 both phases.
// ---------------------------------------------------------------------------
__global__ __launch_bounds__(512, 2) void nnmf_main(
    const unsigned short* __restrict__ X2,
    const unsigned char* __restrict__ W1,
    const unsigned char* __restrict__ W2,
    const float* __restrict__ d0inv,
    const float* __restrict__ h_init,
    float* __restrict__ out)
{
    __shared__ unsigned char  h8_lds[32 * 528];      // 16.9 KB (fp8 h, x256)
    __shared__ unsigned short x_lds[2][32 * 136];    // 17.4 KB (double-buffered)
    __shared__ unsigned char  r8_lds[2][32 * 144];   // 9.2 KB (double-buffered)
    __shared__ float red[8][32];

    const int tid = threadIdx.x;
    const int w  = tid >> 6;        // wave 0..7
    const int l  = tid & 63;
    const int lo = l & 15;
    const int hi = l >> 4;          // 0..3
    const int b0 = blockIdx.x * 32;

    // fp32 h master in registers, C-layout: row=m*16+hi*4+i, col=w*64+nt*16+lo
    float h_reg[2][4][4];
    #pragma unroll
    for (int nt = 0; nt < 4; ++nt) {
        float hv = h_init[w * 64 + nt * 16 + lo];
        #pragma unroll
        for (int m = 0; m < 2; ++m)
            #pragma unroll
            for (int i = 0; i < 4; ++i)
                h_reg[m][nt][i] = hv;
    }

    // x staging: thread -> (row, 16B chunk)
    const int xrow = tid >> 4, xcc = tid & 15;
    const uint4* xg = reinterpret_cast<const uint4*>(X2 + (size_t)(b0 + xrow) * NIN + xcc * 8);
    const int xoff = xrow * 136 + xcc * 8;

    // W base pointers (fp8)
    const unsigned char* w1base = W1 + ((size_t)(w * 16)) * 512 + (size_t)l * 8;   // +s*65536 B, +nc*512 B
    const unsigned char* w2base = W2 + (size_t)(w * 2) * 1024 + (size_t)l * 16;    // +s*65536 B +kc*16384 B +p*1024 B

    // prime: x[0]->buf0, x[1]->buf1, issue x[2]; preload W2[0]
    *reinterpret_cast<uint4*>(&x_lds[0][xoff]) = xg[0];
    *reinterpret_cast<uint4*>(&x_lds[1][xoff]) = xg[16];
    uint4 xnext = xg[32];
    long long w1buf[16];            // fp8 W1 B-frags (valid from it0 s==22 on)
    long long hfr[2][16];           // fp8 h A-frags (loaded per iteration, it>=1)
    uint4 w2v[8];
    #pragma unroll
    for (int kc = 0; kc < 4; ++kc)
        #pragma unroll
        for (int p = 0; p < 2; ++p)
            w2v[kc * 2 + p] = *reinterpret_cast<const uint4*>(
                w2base + (size_t)kc * 16384 + p * 1024);
    __syncthreads();

    const float DSCL = 9.5367431640625e-07f;  // 2^-20: undo h x256 * W1 x4096
    const float TS   = 1.0f / 65536.0f;       // undo W2 x4096 and r x16 scales
    f32x4 tacc[2][4];

    for (int it = 0; it < 5; ++it) {
        // h A-frags: LDS -> regs once per iteration
        if (it != 0) {
            #pragma unroll
            for (int m = 0; m < 2; ++m)
                #pragma unroll
                for (int nc = 0; nc < 16; ++nc)
                    hfr[m][nc] = *reinterpret_cast<const long long*>(
                        &h8_lds[(m * 16 + lo) * 528 + nc * 32 + hi * 8]);
        }

        #pragma unroll
        for (int m = 0; m < 2; ++m)
            #pragma unroll
            for (int nt = 0; nt < 4; ++nt)
                tacc[m][nt] = (f32x4){0.f, 0.f, 0.f, 0.f};

        // ---- prologue: produce r(0) into r8[0]
        {
            f32x4 d0 = {0,0,0,0}, d1 = {0,0,0,0};
            float dv = 0.f;
            if (it == 0) {
                dv = d0inv[w * 16 + lo];
            } else {
                f32x4 a0a = {0,0,0,0}, a0b = {0,0,0,0}, a1a = {0,0,0,0}, a1b = {0,0,0,0};
                #pragma unroll
                for (int nc = 0; nc < 16; nc += 2) {
                    a0a = __builtin_amdgcn_mfma_f32_16x16x32_fp8_fp8(hfr[0][nc],     w1buf[nc],     a0a, 0, 0, 0);
                    a1a = __builtin_amdgcn_mfma_f32_16x16x32_fp8_fp8(hfr[1][nc],     w1buf[nc],     a1a, 0, 0, 0);
                    a0b = __builtin_amdgcn_mfma_f32_16x16x32_fp8_fp8(hfr[0][nc + 1], w1buf[nc + 1], a0b, 0, 0, 0);
                    a1b = __builtin_amdgcn_mfma_f32_16x16x32_fp8_fp8(hfr[1][nc + 1], w1buf[nc + 1], a1b, 0, 0, 0);
                }
                d0 = a0a + a0b;
                d1 = a1a + a1b;
                // reload w1buf = W1[1] (consumed by A(1) at slot 0)
                const unsigned char* w1p = w1base + (size_t)1 * 65536;
                #pragma unroll
                for (int nc = 0; nc < 16; ++nc)
                    w1buf[nc] = *reinterpret_cast<const long long*>(w1p + (size_t)nc * 512);
            }
            #pragma unroll
            for (int i = 0; i < 4; ++i) {
                int row0 = hi * 4 + i;
                float x0 = bf2f(x_lds[0][row0 * 136 + w * 16 + lo]) * 16.0f;
                float x1 = bf2f(x_lds[0][(16 + row0) * 136 + w * 16 + lo]) * 16.0f;
                float r0, r1;
                if (it == 0) { r0 = x0 * dv; r1 = x1 * dv; }
                else {
                    r0 = x0 * __builtin_amdgcn_rcpf(fmaf(d0[i], DSCL, 1e-20f));
                    r1 = x1 * __builtin_amdgcn_rcpf(fmaf(d1[i], DSCL, 1e-20f));
                }
                int c0 = __builtin_amdgcn_cvt_pk_fp8_f32(r0, r0, 0, false);
                int c1 = __builtin_amdgcn_cvt_pk_fp8_f32(r1, r1, 0, false);
                r8_lds[0][row0 * 144 + w * 16 + lo] = (unsigned char)(c0 & 0xff);
                r8_lds[0][(16 + row0) * 144 + w * 16 + lo] = (unsigned char)(c1 & 0xff);
            }
        }
        LDS_BARRIER();

        // ---- pipelined slots: one barrier each
        for (int s = 0; s < 24; ++s) {
            const int bs = s & 1, bn = bs ^ 1;
            const bool last = (s == 23);

            // it0: prefetch exact denom reciprocal for slot s+1
            float dv = 0.f;
            if (it == 0 && !last) dv = d0inv[(s + 1) * 128 + w * 16 + lo];

            // ---- Phase A(s+1): register-only MFMAs (interleaves with B below)
            f32x4 d0 = {0,0,0,0}, d1 = {0,0,0,0};
            if (it != 0 && !last) {
                f32x4 a0a = {0,0,0,0}, a0b = {0,0,0,0}, a1a = {0,0,0,0}, a1b = {0,0,0,0};
                #pragma unroll
                for (int nc = 0; nc < 16; nc += 2) {
                    a0a = __builtin_amdgcn_mfma_f32_16x16x32_fp8_fp8(hfr[0][nc],     w1buf[nc],     a0a, 0, 0, 0);
                    a1a = __builtin_amdgcn_mfma_f32_16x16x32_fp8_fp8(hfr[1][nc],     w1buf[nc],     a1a, 0, 0, 0);
                    a0b = __builtin_amdgcn_mfma_f32_16x16x32_fp8_fp8(hfr[0][nc + 1], w1buf[nc + 1], a0b, 0, 0, 0);
                    a1b = __builtin_amdgcn_mfma_f32_16x16x32_fp8_fp8(hfr[1][nc + 1], w1buf[nc + 1], a1b, 0, 0, 0);
                }
                d0 = a0a + a0b;
                d1 = a1a + a1b;
            }

            // ---- Phase B(s): r8[bs] (written last slot) x w2v (loaded last slot)
            #pragma unroll
            for (int kc = 0; kc < 4; ++kc) {
                long long ra0 = *reinterpret_cast<const long long*>(&r8_lds[bs][lo * 144 + kc * 32 + hi * 8]);
                long long ra1 = *reinterpret_cast<const long long*>(&r8_lds[bs][(16 + lo) * 144 + kc * 32 + hi * 8]);
                #pragma unroll
                for (int p = 0; p < 2; ++p) {
                    union { uint4 v; long long q[2]; } u;
                    u.v = w2v[kc * 2 + p];
                    #pragma unroll
                    for (int h8 = 0; h8 < 2; ++h8) {
                        int nt = p * 2 + h8;
                        tacc[0][nt] = __builtin_amdgcn_mfma_f32_16x16x32_fp8_fp8(ra0, u.q[h8], tacc[0][nt], 0, 0, 0);
                        tacc[1][nt] = __builtin_amdgcn_mfma_f32_16x16x32_fp8_fp8(ra1, u.q[h8], tacc[1][nt], 0, 0, 0);
                    }
                }
            }

            // ---- reload w2v = W2[s+1] (wraps to W2[0] for next iteration)
            if (!(it == 4 && last)) {
                const unsigned char* w2p = w2base + (size_t)(last ? 0 : s + 1) * 65536;
                #pragma unroll
                for (int kc = 0; kc < 4; ++kc)
                    #pragma unroll
                    for (int p = 0; p < 2; ++p)
                        w2v[kc * 2 + p] = *reinterpret_cast<const uint4*>(
                            w2p + (size_t)kc * 16384 + p * 1024);
            }

            // ---- reload w1buf = W1[s+2] (s==22 wraps to W1[0] for next prologue)
            if (!last && (it != 0 || s == 22)) {
                int sw = (s == 22) ? 0 : s + 2;
                const unsigned char* w1p = w1base + (size_t)sw * 65536;
                #pragma unroll
                for (int nc = 0; nc < 16; ++nc)
                    w1buf[nc] = *reinterpret_cast<const long long*>(w1p + (size_t)nc * 512);
            }

            // ---- r(s+1) = 16 * x(s+1) * rcp(denom) -> fp8 in r8[bn]
            if (!last) {
                #pragma unroll
                for (int i = 0; i < 4; ++i) {
                    int row0 = hi * 4 + i;
                    float x0 = bf2f(x_lds[bn][row0 * 136 + w * 16 + lo]) * 16.0f;
                    float x1 = bf2f(x_lds[bn][(16 + row0) * 136 + w * 16 + lo]) * 16.0f;
                    float r0, r1;
                    if (it == 0) { r0 = x0 * dv; r1 = x1 * dv; }
                    else {
                        r0 = x0 * __builtin_amdgcn_rcpf(fmaf(d0[i], DSCL, 1e-20f));
                        r1 = x1 * __builtin_amdgcn_rcpf(fmaf(d1[i], DSCL, 1e-20f));
                    }
                    int c0 = __builtin_amdgcn_cvt_pk_fp8_f32(r0, r0, 0, false);
                    int c1 = __builtin_amdgcn_cvt_pk_fp8_f32(r1, r1, 0, false);
                    r8_lds[bn][row0 * 144 + w * 16 + lo] = (unsigned char)(c0 & 0xff);
                    r8_lds[bn][(16 + row0) * 144 + w * 16 + lo] = (unsigned char)(c1 & 0xff);
                }
            }

            // ---- stage x[s+2] into x_lds[bs]; issue x[s+3]
            *reinterpret_cast<uint4*>(&x_lds[bs][xoff]) = xnext;
            {
                int f = s + 3; if (f >= 24) f -= 24;
                xnext = xg[(size_t)f * 16];
            }

            LDS_BARRIER();
        }

        // ---- boundary: h_new = normalize(h * (1 + t*2^-16)), fp32 in regs
        float p[2][4];
        #pragma unroll
        for (int m = 0; m < 2; ++m)
            #pragma unroll
            for (int i = 0; i < 4; ++i) p[m][i] = 0.f;

        #pragma unroll
        for (int m = 0; m < 2; ++m)
            #pragma unroll
            for (int nt = 0; nt < 4; ++nt)
                #pragma unroll
                for (int i = 0; i < 4; ++i) {
                    float v = h_reg[m][nt][i] * (1.f + tacc[m][nt][i] * TS);  // EPSILON_0 = 1
                    h_reg[m][nt][i] = v;
                    p[m][i] += v;
                }
        #pragma unroll
        for (int mask = 1; mask < 16; mask <<= 1)
            #pragma unroll
            for (int m = 0; m < 2; ++m)
                #pragma unroll
                for (int i = 0; i < 4; ++i)
                    p[m][i] += __shfl_xor(p[m][i], mask, 64);
        if (lo == 0) {
            #pragma unroll
            for (int m = 0; m < 2; ++m)
                #pragma unroll
                for (int i = 0; i < 4; ++i)
                    red[w][m * 16 + hi * 4 + i] = p[m][i];
        }
        __syncthreads();
        float inv[2][4];
        #pragma unroll
        for (int m = 0; m < 2; ++m)
            #pragma unroll
            for (int i = 0; i < 4; ++i) {
                int row = m * 16 + hi * 4 + i;
                float S = 0.f;
                #pragma unroll
                for (int ww = 0; ww < 8; ++ww) S += red[ww][row];
                inv[m][i] = 1.f / (S + 1e-20f);
            }

        if (it < 4) {
            #pragma unroll
            for (int m = 0; m < 2; ++m)
                #pragma unroll
                for (int nt = 0; nt < 4; ++nt)
                    #pragma unroll
                    for (int i = 0; i < 4; ++i) {
                        int row = m * 16 + hi * 4 + i;
                        int col = w * 64 + nt * 16 + lo;
                        float hv = h_reg[m][nt][i] * inv[m][i];
                        h_reg[m][nt][i] = hv;
                        int c = __builtin_amdgcn_cvt_pk_fp8_f32(hv * 256.0f, hv * 256.0f, 0, false);
                        h8_lds[row * 528 + col] = (unsigned char)(c & 0xff);
                    }
            __syncthreads();
        } else {
            #pragma unroll
            for (int m = 0; m < 2; ++m)
                #pragma unroll
                for (int nt = 0; nt < 4; ++nt)
                    #pragma unroll
                    for (int i = 0; i < 4; ++i) {
                        int row = m * 16 + hi * 4 + i;
                        int col = w * 64 + nt * 16 + lo;
                        out[(size_t)(b0 + row) * 512 + col] = h_reg[m][nt][i] * inv[m][i];
                    }
        }
    }
}

extern "C" void kernel_launch(void* const* d_in, const int* in_sizes, int n_in,
                              void* d_out, int out_size, void* d_ws, size_t ws_size,
                              hipStream_t stream) {
    const float* x   = (const float*)d_in[0];   // [8192][3072]
    const float* wgt = (const float*)d_in[1];   // [512][3072]
    const float* h0  = (const float*)d_in[2];   // [512]
    float* out = (float*)d_out;

    // ws: X2 bf16 50,331,648 | W1 fp8 1,572,864 | W2 fp8 1,572,864 | d0inv 12,288
    unsigned short* X2 = (unsigned short*)d_ws;
    unsigned char*  W1 = (unsigned char*)((char*)d_ws + 50331648);
    unsigned char*  W2 = (unsigned char*)((char*)d_ws + 51904512);
    float* d0inv       = (float*)((char*)d_ws + 53477376);

    prep_w<<<1152, 256, 0, stream>>>(wgt, W1, W2);
    prep_cs<<<12, 256, 0, stream>>>(wgt, h0, d0inv);
    prep_x<<<8192, 256, 0, stream>>>(x, X2);
    nnmf_main<<<256, 512, 0, stream>>>(X2, W1, W2, d0inv, h0, out);
}

// Round 3
// 508.500 us; speedup vs baseline: 1.0772x; 1.0772x over previous
//
#include <hip/hip_runtime.h>

// NNMF fused: B=8192, NIN=3072, NOUT=512, 5 iterations.
// R9: register-cap fix + fused prep.
//  R7/R8 rocprof: VGPR_Count pinned at 128 by __launch_bounds__(512,2) while
//  the intended live set (hfr 64 + w1buf 32 + tacc 32 + h_reg 32 + addr) is
//  >=160 regs -> "register-resident h" never happened; allocator re-loaded
//  hfr per slot, and R8's fused region (d0/d1 + double w2v live) regressed
//  (382 vs 328 us). Grid = 256 blocks = 1 block/CU regardless, so the
//  (512,2) thrift bought nothing. Fix: __launch_bounds__(512,1) -> backend
//  caps at 256 VGPR (2 waves/SIMD structural), same 8 waves/CU occupancy.
//  Structure reverted to R7 two-barrier slots (best measured).
//  Also: 3 prep launches fused into one (9440-block) kernel; it0 denom
//  column-sum parallelized 8x over n-chunks into d0part[8][3072]; main's it0
//  path sums 8 partials + precise div (deterministic). Was ~180 us of
//  serialized prep (prep_cs: 12 CUs x 512 latency-bound loads/thread).

#define NIN 3072
#define NOUT 512

using f32x4  = __attribute__((ext_vector_type(4))) float;

__device__ __forceinline__ unsigned short f2bf(float f) {
    unsigned int u = __builtin_bit_cast(unsigned int, f);
    return (unsigned short)((u + 0x7fffu + ((u >> 16) & 1u)) >> 16);  // RNE
}
__device__ __forceinline__ float bf2f(unsigned short s) {
    unsigned int u = ((unsigned int)s) << 16;
    return __builtin_bit_cast(float, u);
}

// LDS-only barrier: cross-wave deps in the slot loop are LDS-only; global
// prefetches stay in flight (consumed by issuing wave, compiler inserts vmcnt).
#define LDS_BARRIER() do {                                   \
    asm volatile("s_waitcnt lgkmcnt(0)" ::: "memory");       \
    __builtin_amdgcn_s_barrier();                            \
    asm volatile("" ::: "memory");                           \
} while (0)

// ---------------------------------------------------------------------------
// prep_all: one launch, 9440 blocks x 256 threads.
//   blocks [0,8192)        : per-row x normalize -> bf16 X2
//   blocks [8192,9344)     : W -> W2 (fp8 pair-packed) and W1 (fp8 A-phase frags)
//   blocks [9344,9440)     : it0 denom partials d0part[nch][k], nch=u/12, kb=u%12
// Layouts (verified R2-R7):
//   W2 byte addr = ((kcg*16+pr)*64+l)*16 + h8*8 + j
//     element: n=(pr*2+h8)*16+(l&15), k=kcg*32+(l>>4)*8+j, scale x4096
//   W1[((ktg*16+nc)*64+l)*8+j] = fp8(W[nc*32+(l>>4)*8+j][ktg*16+(l&15)]*4096)
// ---------------------------------------------------------------------------
__global__ void prep_all(const float* __restrict__ x,
                         const float* __restrict__ W,
                         const float* __restrict__ h_init,
                         unsigned short* __restrict__ X2,
                         unsigned char* __restrict__ W1,
                         unsigned char* __restrict__ W2,
                         float* __restrict__ d0part) {
    __shared__ float wsum[4];
    const int bb = blockIdx.x;
    const int t  = threadIdx.x;

    if (bb < 8192) {
        // ---- x row normalize -> bf16
        const int b = bb;
        const float4* r4 = reinterpret_cast<const float4*>(x + (size_t)b * NIN);
        float s = 0.f;
        float4 v0 = r4[t], v1 = r4[t + 256], v2 = r4[t + 512];
        s = v0.x + v0.y + v0.z + v0.w + v1.x + v1.y + v1.z + v1.w + v2.x + v2.y + v2.z + v2.w;
        #pragma unroll
        for (int off = 32; off > 0; off >>= 1) s += __shfl_down(s, off, 64);
        int w = t >> 6, l = t & 63;
        if (l == 0) wsum[w] = s;
        __syncthreads();
        float inv = 1.0f / (wsum[0] + wsum[1] + wsum[2] + wsum[3] + 1e-20f);
        unsigned short* orow = X2 + (size_t)b * NIN;
        #pragma unroll
        for (int c = 0; c < 3; ++c) {
            float4 v = (c == 0) ? v0 : (c == 1) ? v1 : v2;
            ushort4 o;
            o.x = f2bf(v.x * inv); o.y = f2bf(v.y * inv);
            o.z = f2bf(v.z * inv); o.w = f2bf(v.w * inv);
            *reinterpret_cast<ushort4*>(orow + (t + c * 256) * 4) = o;
        }
    } else if (bb < 8192 + 1152) {
        // ---- W quantization
        int tt = (bb - 8192) * 256 + t;       // 0 .. 294911
        if (tt < 98304) {
            int f = tt >> 6, l = tt & 63;
            int kcg = f >> 4, pr = f & 15;
            int kbase = kcg * 32 + ((l >> 4) << 3);
            unsigned int words[4];
            #pragma unroll
            for (int h8 = 0; h8 < 2; ++h8) {
                int n = (pr * 2 + h8) * 16 + (l & 15);
                const float* src = W + (size_t)n * NIN + kbase;
                float v[8];
                #pragma unroll
                for (int j = 0; j < 8; ++j) v[j] = src[j] * 4096.0f;
                int lo32 = __builtin_amdgcn_cvt_pk_fp8_f32(v[0], v[1], 0, false);
                lo32     = __builtin_amdgcn_cvt_pk_fp8_f32(v[2], v[3], lo32, true);
                int hi32 = __builtin_amdgcn_cvt_pk_fp8_f32(v[4], v[5], 0, false);
                hi32     = __builtin_amdgcn_cvt_pk_fp8_f32(v[6], v[7], hi32, true);
                words[h8 * 2]     = (unsigned int)lo32;
                words[h8 * 2 + 1] = (unsigned int)hi32;
            }
            *reinterpret_cast<uint4*>(W2 + (size_t)tt * 16) =
                *reinterpret_cast<uint4*>(words);
        } else {
            int u = tt - 98304;               // 0 .. 196607
            int f = u >> 6, l = u & 63;
            int ktg = f >> 4, nc = f & 15;
            int k = ktg * 16 + (l & 15);
            int nb = nc * 32 + ((l >> 4) << 3);
            float v[8];
            #pragma unroll
            for (int j = 0; j < 8; ++j) v[j] = W[(size_t)(nb + j) * NIN + k] * 4096.0f;
            int lo32 = __builtin_amdgcn_cvt_pk_fp8_f32(v[0], v[1], 0, false);
            lo32     = __builtin_amdgcn_cvt_pk_fp8_f32(v[2], v[3], lo32, true);
            int hi32 = __builtin_amdgcn_cvt_pk_fp8_f32(v[4], v[5], 0, false);
            hi32     = __builtin_amdgcn_cvt_pk_fp8_f32(v[6], v[7], hi32, true);
            uint2 o; o.x = (unsigned int)lo32; o.y = (unsigned int)hi32;
            *reinterpret_cast<uint2*>(W1 + (size_t)u * 8) = o;
        }
    } else {
        // ---- it0 denom partials: d0part[nch][k] = sum_{n in chunk} h0[n]*W[n][k]
        int u = bb - 9344;                    // 0..95
        int nch = u / 12, kb = u % 12;
        int k = kb * 256 + t;
        int n0 = nch * 64;
        float s = 0.f;
        const float* p = W + (size_t)n0 * NIN + k;
        #pragma unroll 8
        for (int n = 0; n < 64; ++n) s += h_init[n0 + n] * p[(size_t)n * NIN];
        d0part[(size_t)nch * NIN + k] = s;
    }
}

// ---------------------------------------------------------------------------
// Main kernel. 256 blocks x 512 threads (8 waves), 32 rows/block, 1 block/CU.
// R7 two-barrier slot structure; fp8 both phases; 256-VGPR budget.
// ---------------------------------------------------------------------------
__global__ __launch_bounds__(512, 1) void nnmf_main(
    const unsigned short* __restrict__ X2,
    const unsigned char* __restrict__ W1,
    const unsigned char* __restrict__ W2,
    const float* __restrict__ d0part,
    const float* __restrict__ h_init,
    float* __restrict__ out)
{
    __shared__ unsigned char  h8_lds[32 * 528];  // 16.9 KB (fp8 h, x256)
    __shared__ unsigned short x_lds[32 * 136];   // 8.7 KB
    __shared__ unsigned char  r8_lds[32 * 144];  // 4.6 KB (fp8 r, stride 144B)
    __shared__ float red[8][32];

    const int tid = threadIdx.x;
    const int w  = tid >> 6;        // wave 0..7
    const int l  = tid & 63;
    const int lo = l & 15;
    const int hi = l >> 4;          // 0..3
    const int b0 = blockIdx.x * 32;

    // fp32 h master in registers, C-layout: row=m*16+hi*4+i, col=w*64+nt*16+lo
    float h_reg[2][4][4];
    #pragma unroll
    for (int nt = 0; nt < 4; ++nt) {
        float hv = h_init[w * 64 + nt * 16 + lo];
        #pragma unroll
        for (int m = 0; m < 2; ++m)
            #pragma unroll
            for (int i = 0; i < 4; ++i)
                h_reg[m][nt][i] = hv;
    }

    // x staging: thread -> (row, 16B chunk)
    const int xrow = tid >> 4, xcc = tid & 15;
    const uint4* xg = reinterpret_cast<const uint4*>(X2 + (size_t)(b0 + xrow) * NIN + xcc * 8);
    unsigned short* xdst = &x_lds[xrow * 136 + xcc * 8];

    // W base pointers (fp8)
    const unsigned char* w1base = W1 + ((size_t)(w * 16)) * 512 + (size_t)l * 8;   // +s*65536 B, +nc*512 B
    const unsigned char* w2base = W2 + (size_t)(w * 2) * 1024 + (size_t)l * 16;    // +s*65536 B +kc*16384 B +p*1024 B

    // prime pipeline: x[0] -> LDS, x[1] -> reg
    *reinterpret_cast<uint4*>(xdst) = xg[0];
    uint4 xnext = xg[16];
    long long w1buf[16];            // fp8 W1 B-frags (valid from it0 s==23 on)
    long long hfr[2][16];           // fp8 h A-frags (loaded per iteration, it>=1)
    __syncthreads();

    const float DSCL = 9.5367431640625e-07f;  // 2^-20: undo h x256 * W1 x4096
    const float TS   = 1.0f / 65536.0f;       // undo W2 x4096 and r x16 scales
    f32x4 tacc[2][4];

    for (int it = 0; it < 5; ++it) {
        // h A-frags: LDS -> regs once per iteration (256-VGPR budget keeps live)
        if (it != 0) {
            #pragma unroll
            for (int m = 0; m < 2; ++m)
                #pragma unroll
                for (int nc = 0; nc < 16; ++nc)
                    hfr[m][nc] = *reinterpret_cast<const long long*>(
                        &h8_lds[(m * 16 + lo) * 528 + nc * 32 + hi * 8]);
        }

        #pragma unroll
        for (int m = 0; m < 2; ++m)
            #pragma unroll
            for (int nt = 0; nt < 4; ++nt)
                tacc[m][nt] = (f32x4){0.f, 0.f, 0.f, 0.f};

        for (int s = 0; s < 24; ++s) {
            const int sn  = (s + 1 == 24) ? 0 : s + 1;
            const int sn2 = (s + 2 >= 24) ? (s + 2 - 24) : s + 2;

            // ---- issue x[s+2] prefetch a full slot early (drained by next slot)
            uint4 xfut = xg[sn2 * 16];

            // ---- issue W2[s] fp8 loads (8 x dwordx4 = 16 frags; consumed in Phase B)
            uint4 w2v[8];
            {
                const unsigned char* w2p = w2base + (size_t)s * 65536;
                #pragma unroll
                for (int kc = 0; kc < 4; ++kc)
                    #pragma unroll
                    for (int p = 0; p < 2; ++p)
                        w2v[kc * 2 + p] = *reinterpret_cast<const uint4*>(
                            w2p + (size_t)kc * 16384 + p * 1024);
            }

            f32x4 d0, d1;
            float dv = 0.f;
            if (it == 0) {
                // exact it0 denom: sum 8 partials + precise div
                const float* dp = d0part + s * 128 + w * 16 + lo;
                float sm = 1e-20f;
                #pragma unroll
                for (int j = 0; j < 8; ++j) sm += dp[(size_t)j * NIN];
                dv = 1.0f / sm;
            } else {
                // ---- Phase A (fp8): denom tiles, h and W1 operands register-resident
                f32x4 a0a = {0,0,0,0}, a0b = {0,0,0,0}, a1a = {0,0,0,0}, a1b = {0,0,0,0};
                #pragma unroll
                for (int nc = 0; nc < 16; nc += 2) {
                    a0a = __builtin_amdgcn_mfma_f32_16x16x32_fp8_fp8(hfr[0][nc],     w1buf[nc],     a0a, 0, 0, 0);
                    a1a = __builtin_amdgcn_mfma_f32_16x16x32_fp8_fp8(hfr[1][nc],     w1buf[nc],     a1a, 0, 0, 0);
                    a0b = __builtin_amdgcn_mfma_f32_16x16x32_fp8_fp8(hfr[0][nc + 1], w1buf[nc + 1], a0b, 0, 0, 0);
                    a1b = __builtin_amdgcn_mfma_f32_16x16x32_fp8_fp8(hfr[1][nc + 1], w1buf[nc + 1], a1b, 0, 0, 0);
                }
                d0 = a0a + a0b;
                d1 = a1a + a1b;
            }

            // ---- r = 16 * x * rcp(denom + eps) -> fp8 in r8_lds
            #pragma unroll
            for (int i = 0; i < 4; ++i) {
                int row0 = hi * 4 + i;
                float x0 = bf2f(x_lds[row0 * 136 + w * 16 + lo]) * 16.0f;
                float x1 = bf2f(x_lds[(16 + row0) * 136 + w * 16 + lo]) * 16.0f;
                float r0, r1;
                if (it == 0) { r0 = x0 * dv; r1 = x1 * dv; }
                else {
                    r0 = x0 * __builtin_amdgcn_rcpf(fmaf(d0[i], DSCL, 1e-20f));
                    r1 = x1 * __builtin_amdgcn_rcpf(fmaf(d1[i], DSCL, 1e-20f));
                }
                int c0 = __builtin_amdgcn_cvt_pk_fp8_f32(r0, r0, 0, false);
                int c1 = __builtin_amdgcn_cvt_pk_fp8_f32(r1, r1, 0, false);
                r8_lds[row0 * 144 + w * 16 + lo] = (unsigned char)(c0 & 0xff);
                r8_lds[(16 + row0) * 144 + w * 16 + lo] = (unsigned char)(c1 & 0xff);
            }
            LDS_BARRIER();   // barrier A (LDS-only: global prefetches stay in flight)

            // ---- Phase B 1st half (kc 0,1), fp8 MFMA
            #pragma unroll
            for (int kc = 0; kc < 2; ++kc) {
                long long ra0 = *reinterpret_cast<const long long*>(&r8_lds[lo * 144 + kc * 32 + hi * 8]);
                long long ra1 = *reinterpret_cast<const long long*>(&r8_lds[(16 + lo) * 144 + kc * 32 + hi * 8]);
                #pragma unroll
                for (int p = 0; p < 2; ++p) {
                    union { uint4 v; long long q[2]; } u;
                    u.v = w2v[kc * 2 + p];
                    #pragma unroll
                    for (int h8 = 0; h8 < 2; ++h8) {
                        int nt = p * 2 + h8;
                        tacc[0][nt] = __builtin_amdgcn_mfma_f32_16x16x32_fp8_fp8(ra0, u.q[h8], tacc[0][nt], 0, 0, 0);
                        tacc[1][nt] = __builtin_amdgcn_mfma_f32_16x16x32_fp8_fp8(ra1, u.q[h8], tacc[1][nt], 0, 0, 0);
                    }
                }
            }

            // ---- reload w1buf with W1[sn] fp8 (skip during it0 except last slot)
            if (it > 0 || s == 23) {
                const unsigned char* w1p = w1base + (size_t)sn * 65536;
                #pragma unroll
                for (int nc = 0; nc < 16; ++nc)
                    w1buf[nc] = *reinterpret_cast<const long long*>(w1p + (size_t)nc * 512);
            }

            // ---- Phase B 2nd half (kc 2,3)
            #pragma unroll
            for (int kc = 2; kc < 4; ++kc) {
                long long ra0 = *reinterpret_cast<const long long*>(&r8_lds[lo * 144 + kc * 32 + hi * 8]);
                long long ra1 = *reinterpret_cast<const long long*>(&r8_lds[(16 + lo) * 144 + kc * 32 + hi * 8]);
                #pragma unroll
                for (int p = 0; p < 2; ++p) {
                    union { uint4 v; long long q[2]; } u;
                    u.v = w2v[kc * 2 + p];
                    #pragma unroll
                    for (int h8 = 0; h8 < 2; ++h8) {
                        int nt = p * 2 + h8;
                        tacc[0][nt] = __builtin_amdgcn_mfma_f32_16x16x32_fp8_fp8(ra0, u.q[h8], tacc[0][nt], 0, 0, 0);
                        tacc[1][nt] = __builtin_amdgcn_mfma_f32_16x16x32_fp8_fp8(ra1, u.q[h8], tacc[1][nt], 0, 0, 0);
                    }
                }
            }

            // ---- stage x[s+1] (loaded a slot+ ago), rotate prefetch regs
            *reinterpret_cast<uint4*>(xdst) = xnext;
            xnext = xfut;
            LDS_BARRIER();   // barrier B
        }

        // ---- boundary: h_new = normalize(h * (1 + t*2^-16)), fp32 in regs
        float p[2][4];
        #pragma unroll
        for (int m = 0; m < 2; ++m)
            #pragma unroll
            for (int i = 0; i < 4; ++i) p[m][i] = 0.f;

        #pragma unroll
        for (int m = 0; m < 2; ++m)
            #pragma unroll
            for (int nt = 0; nt < 4; ++nt)
                #pragma unroll
                for (int i = 0; i < 4; ++i) {
                    float v = h_reg[m][nt][i] * (1.f + tacc[m][nt][i] * TS);  // EPSILON_0 = 1
                    h_reg[m][nt][i] = v;
                    p[m][i] += v;
                }
        #pragma unroll
        for (int mask = 1; mask < 16; mask <<= 1)
            #pragma unroll
            for (int m = 0; m < 2; ++m)
                #pragma unroll
                for (int i = 0; i < 4; ++i)
                    p[m][i] += __shfl_xor(p[m][i], mask, 64);
        if (lo == 0) {
            #pragma unroll
            for (int m = 0; m < 2; ++m)
                #pragma unroll
                for (int i = 0; i < 4; ++i)
                    red[w][m * 16 + hi * 4 + i] = p[m][i];
        }
        __syncthreads();
        float inv[2][4];
        #pragma unroll
        for (int m = 0; m < 2; ++m)
            #pragma unroll
            for (int i = 0; i < 4; ++i) {
                int row = m * 16 + hi * 4 + i;
                float S = 0.f;
                #pragma unroll
                for (int ww = 0; ww < 8; ++ww) S += red[ww][row];
                inv[m][i] = 1.f / (S + 1e-20f);
            }

        if (it < 4) {
            #pragma unroll
            for (int m = 0; m < 2; ++m)
                #pragma unroll
                for (int nt = 0; nt < 4; ++nt)
                    #pragma unroll
                    for (int i = 0; i < 4; ++i) {
                        int row = m * 16 + hi * 4 + i;
                        int col = w * 64 + nt * 16 + lo;
                        float hv = h_reg[m][nt][i] * inv[m][i];
                        h_reg[m][nt][i] = hv;
                        int c = __builtin_amdgcn_cvt_pk_fp8_f32(hv * 256.0f, hv * 256.0f, 0, false);
                        h8_lds[row * 528 + col] = (unsigned char)(c & 0xff);
                    }
            __syncthreads();
        } else {
            #pragma unroll
            for (int m = 0; m < 2; ++m)
                #pragma unroll
                for (int nt = 0; nt < 4; ++nt)
                    #pragma unroll
                    for (int i = 0; i < 4; ++i) {
                        int row = m * 16 + hi * 4 + i;
                        int col = w * 64 + nt * 16 + lo;
                        out[(size_t)(b0 + row) * 512 + col] = h_reg[m][nt][i] * inv[m][i];
                    }
        }
    }
}

extern "C" void kernel_launch(void* const* d_in, const int* in_sizes, int n_in,
                              void* d_out, int out_size, void* d_ws, size_t ws_size,
                              hipStream_t stream) {
    const float* x   = (const float*)d_in[0];   // [8192][3072]
    const float* wgt = (const float*)d_in[1];   // [512][3072]
    const float* h0  = (const float*)d_in[2];   // [512]
    float* out = (float*)d_out;

    // ws: X2 bf16 50,331,648 | W1 fp8 1,572,864 | W2 fp8 1,572,864 | d0part 98,304
    unsigned short* X2 = (unsigned short*)d_ws;
    unsigned char*  W1 = (unsigned char*)((char*)d_ws + 50331648);
    unsigned char*  W2 = (unsigned char*)((char*)d_ws + 51904512);
    float* d0part      = (float*)((char*)d_ws + 53477376);

    prep_all<<<9440, 256, 0, stream>>>(x, wgt, h0, X2, W1, W2, d0part);
    nnmf_main<<<256, 512, 0, stream>>>(X2, W1, W2, d0part, h0, out);
}

// Round 4
// 469.972 us; speedup vs baseline: 1.1655x; 1.0820x over previous
//
#include <hip/hip_runtime.h>

// NNMF fused: B=8192, NIN=3072, NOUT=512, 5 iterations.
// R10: force the 256-VGPR budget with amdgpu_waves_per_eu(2,2).
//  R7/R9 evidence: compiler pins VGPR=128 under both __launch_bounds__(512,2)
//  and (512,1) -- its occupancy heuristic targets 4 waves/SIMD and
//  rematerializes the hfr LDS reads (32 x ds_read_b64/wave/slot = 128 KB/CU/
//  slot, ~1000 cy) instead of keeping them live. launch_bounds minimums can't
//  forbid that; waves_per_eu(2,2) sets MAX waves/EU = 2 -> 256-reg budget,
//  no occupancy incentive. Grid = 256 blocks = 1 block/CU, so nothing lost.
//  Slot structure = R7 two-barrier (best measured, 328 us); with hfr/w1buf/
//  w2v/tacc/h_reg all resident (~220 regs) Phase A is pure register MFMA.
//  Prep: single prep_all launch also computes d0inv (96 blocks, coalesced k,
//  8-way n-split + LDS reduce); main it0 path = exact single d0inv load (R7).

#define NIN 3072
#define NOUT 512

using f32x4  = __attribute__((ext_vector_type(4))) float;

__device__ __forceinline__ unsigned short f2bf(float f) {
    unsigned int u = __builtin_bit_cast(unsigned int, f);
    return (unsigned short)((u + 0x7fffu + ((u >> 16) & 1u)) >> 16);  // RNE
}
__device__ __forceinline__ float bf2f(unsigned short s) {
    unsigned int u = ((unsigned int)s) << 16;
    return __builtin_bit_cast(float, u);
}

// LDS-only barrier: cross-wave deps in the slot loop are LDS-only; global
// prefetches stay in flight (consumed by issuing wave, compiler inserts vmcnt).
#define LDS_BARRIER() do {                                   \
    asm volatile("s_waitcnt lgkmcnt(0)" ::: "memory");       \
    __builtin_amdgcn_s_barrier();                            \
    asm volatile("" ::: "memory");                           \
} while (0)

// ---------------------------------------------------------------------------
// prep_all: one launch, 9440 blocks x 256 threads.
//   blocks [0,8192)     : per-row x normalize -> bf16 X2
//   blocks [8192,9344)  : W -> W2 (fp8 pair-packed) and W1 (fp8 A-phase frags)
//   blocks [9344,9440)  : d0inv[k] = 1/(sum_n h0[n]*W[n][k] + 1e-20)
//                         (block owns 32 k; 8-way n-split; coalesced k-mapping)
// Layouts (verified R2-R9):
//   W2 byte addr = ((kcg*16+pr)*64+l)*16 + h8*8 + j
//     element: n=(pr*2+h8)*16+(l&15), k=kcg*32+(l>>4)*8+j, scale x4096
//   W1[((ktg*16+nc)*64+l)*8+j] = fp8(W[nc*32+(l>>4)*8+j][ktg*16+(l&15)]*4096)
// ---------------------------------------------------------------------------
__global__ void prep_all(const float* __restrict__ x,
                         const float* __restrict__ W,
                         const float* __restrict__ h_init,
                         unsigned short* __restrict__ X2,
                         unsigned char* __restrict__ W1,
                         unsigned char* __restrict__ W2,
                         float* __restrict__ d0inv) {
    __shared__ float wsum[4];
    __shared__ float dred[8][32];
    const int bb = blockIdx.x;
    const int t  = threadIdx.x;

    if (bb < 8192) {
        // ---- x row normalize -> bf16
        const int b = bb;
        const float4* r4 = reinterpret_cast<const float4*>(x + (size_t)b * NIN);
        float s = 0.f;
        float4 v0 = r4[t], v1 = r4[t + 256], v2 = r4[t + 512];
        s = v0.x + v0.y + v0.z + v0.w + v1.x + v1.y + v1.z + v1.w + v2.x + v2.y + v2.z + v2.w;
        #pragma unroll
        for (int off = 32; off > 0; off >>= 1) s += __shfl_down(s, off, 64);
        int w = t >> 6, l = t & 63;
        if (l == 0) wsum[w] = s;
        __syncthreads();
        float inv = 1.0f / (wsum[0] + wsum[1] + wsum[2] + wsum[3] + 1e-20f);
        unsigned short* orow = X2 + (size_t)b * NIN;
        #pragma unroll
        for (int c = 0; c < 3; ++c) {
            float4 v = (c == 0) ? v0 : (c == 1) ? v1 : v2;
            ushort4 o;
            o.x = f2bf(v.x * inv); o.y = f2bf(v.y * inv);
            o.z = f2bf(v.z * inv); o.w = f2bf(v.w * inv);
            *reinterpret_cast<ushort4*>(orow + (t + c * 256) * 4) = o;
        }
    } else if (bb < 8192 + 1152) {
        // ---- W quantization
        int tt = (bb - 8192) * 256 + t;       // 0 .. 294911
        if (tt < 98304) {
            int f = tt >> 6, l = tt & 63;
            int kcg = f >> 4, pr = f & 15;
            int kbase = kcg * 32 + ((l >> 4) << 3);
            unsigned int words[4];
            #pragma unroll
            for (int h8 = 0; h8 < 2; ++h8) {
                int n = (pr * 2 + h8) * 16 + (l & 15);
                const float* src = W + (size_t)n * NIN + kbase;
                float v[8];
                #pragma unroll
                for (int j = 0; j < 8; ++j) v[j] = src[j] * 4096.0f;
                int lo32 = __builtin_amdgcn_cvt_pk_fp8_f32(v[0], v[1], 0, false);
                lo32     = __builtin_amdgcn_cvt_pk_fp8_f32(v[2], v[3], lo32, true);
                int hi32 = __builtin_amdgcn_cvt_pk_fp8_f32(v[4], v[5], 0, false);
                hi32     = __builtin_amdgcn_cvt_pk_fp8_f32(v[6], v[7], hi32, true);
                words[h8 * 2]     = (unsigned int)lo32;
                words[h8 * 2 + 1] = (unsigned int)hi32;
            }
            *reinterpret_cast<uint4*>(W2 + (size_t)tt * 16) =
                *reinterpret_cast<uint4*>(words);
        } else {
            int u = tt - 98304;               // 0 .. 196607
            int f = u >> 6, l = u & 63;
            int ktg = f >> 4, nc = f & 15;
            int k = ktg * 16 + (l & 15);
            int nb = nc * 32 + ((l >> 4) << 3);
            float v[8];
            #pragma unroll
            for (int j = 0; j < 8; ++j) v[j] = W[(size_t)(nb + j) * NIN + k] * 4096.0f;
            int lo32 = __builtin_amdgcn_cvt_pk_fp8_f32(v[0], v[1], 0, false);
            lo32     = __builtin_amdgcn_cvt_pk_fp8_f32(v[2], v[3], lo32, true);
            int hi32 = __builtin_amdgcn_cvt_pk_fp8_f32(v[4], v[5], 0, false);
            hi32     = __builtin_amdgcn_cvt_pk_fp8_f32(v[6], v[7], hi32, true);
            uint2 o; o.x = (unsigned int)lo32; o.y = (unsigned int)hi32;
            *reinterpret_cast<uint2*>(W1 + (size_t)u * 8) = o;
        }
    } else {
        // ---- d0inv: block owns 32 k-cols; thread (kid = t&31, nsub = t>>5)
        int kb = bb - 9344;                   // 0..95
        int kid = t & 31, nsub = t >> 5;      // 8 n-chunks of 64
        int k = kb * 32 + kid;
        int n0 = nsub * 64;
        float s = 0.f;
        const float* p = W + (size_t)n0 * NIN + k;
        #pragma unroll 8
        for (int n = 0; n < 64; ++n) s += h_init[n0 + n] * p[(size_t)n * NIN];
        dred[nsub][kid] = s;
        __syncthreads();
        if (t < 32) {
            float sm = 1e-20f;
            #pragma unroll
            for (int j = 0; j < 8; ++j) sm += dred[j][t];
            d0inv[kb * 32 + t] = 1.0f / sm;
        }
    }
}

// ---------------------------------------------------------------------------
// Main kernel. 256 blocks x 512 threads (8 waves), 32 rows/block, 1 block/CU.
// R7 two-barrier slot structure; fp8 both phases; 256-VGPR budget via
// waves_per_eu(2,2) so hfr/w1buf/w2v/tacc/h_reg stay register-resident.
// ---------------------------------------------------------------------------
__global__ __launch_bounds__(512)
__attribute__((amdgpu_waves_per_eu(2, 2)))
void nnmf_main(
    const unsigned short* __restrict__ X2,
    const unsigned char* __restrict__ W1,
    const unsigned char* __restrict__ W2,
    const float* __restrict__ d0inv,
    const float* __restrict__ h_init,
    float* __restrict__ out)
{
    __shared__ unsigned char  h8_lds[32 * 528];  // 16.9 KB (fp8 h, x256)
    __shared__ unsigned short x_lds[32 * 136];   // 8.7 KB
    __shared__ unsigned char  r8_lds[32 * 144];  // 4.6 KB (fp8 r, stride 144B)
    __shared__ float red[8][32];

    const int tid = threadIdx.x;
    const int w  = tid >> 6;        // wave 0..7
    const int l  = tid & 63;
    const int lo = l & 15;
    const int hi = l >> 4;          // 0..3
    const int b0 = blockIdx.x * 32;

    // fp32 h master in registers, C-layout: row=m*16+hi*4+i, col=w*64+nt*16+lo
    float h_reg[2][4][4];
    #pragma unroll
    for (int nt = 0; nt < 4; ++nt) {
        float hv = h_init[w * 64 + nt * 16 + lo];
        #pragma unroll
        for (int m = 0; m < 2; ++m)
            #pragma unroll
            for (int i = 0; i < 4; ++i)
                h_reg[m][nt][i] = hv;
    }

    // x staging: thread -> (row, 16B chunk)
    const int xrow = tid >> 4, xcc = tid & 15;
    const uint4* xg = reinterpret_cast<const uint4*>(X2 + (size_t)(b0 + xrow) * NIN + xcc * 8);
    unsigned short* xdst = &x_lds[xrow * 136 + xcc * 8];

    // W base pointers (fp8)
    const unsigned char* w1base = W1 + ((size_t)(w * 16)) * 512 + (size_t)l * 8;   // +s*65536 B, +nc*512 B
    const unsigned char* w2base = W2 + (size_t)(w * 2) * 1024 + (size_t)l * 16;    // +s*65536 B +kc*16384 B +p*1024 B

    // prime pipeline: x[0] -> LDS, x[1] -> reg
    *reinterpret_cast<uint4*>(xdst) = xg[0];
    uint4 xnext = xg[16];
    long long w1buf[16];            // fp8 W1 B-frags (valid from it0 s==23 on)
    long long hfr[2][16];           // fp8 h A-frags (loaded per iteration, it>=1)
    __syncthreads();

    const float DSCL = 9.5367431640625e-07f;  // 2^-20: undo h x256 * W1 x4096
    const float TS   = 1.0f / 65536.0f;       // undo W2 x4096 and r x16 scales
    f32x4 tacc[2][4];

    for (int it = 0; it < 5; ++it) {
        // h A-frags: LDS -> regs once per iteration (register-resident after)
        if (it != 0) {
            #pragma unroll
            for (int m = 0; m < 2; ++m)
                #pragma unroll
                for (int nc = 0; nc < 16; ++nc)
                    hfr[m][nc] = *reinterpret_cast<const long long*>(
                        &h8_lds[(m * 16 + lo) * 528 + nc * 32 + hi * 8]);
        }

        #pragma unroll
        for (int m = 0; m < 2; ++m)
            #pragma unroll
            for (int nt = 0; nt < 4; ++nt)
                tacc[m][nt] = (f32x4){0.f, 0.f, 0.f, 0.f};

        for (int s = 0; s < 24; ++s) {
            const int sn  = (s + 1 == 24) ? 0 : s + 1;
            const int sn2 = (s + 2 >= 24) ? (s + 2 - 24) : s + 2;

            // ---- issue x[s+2] prefetch a full slot early (drained by next slot)
            uint4 xfut = xg[sn2 * 16];

            // ---- issue W2[s] fp8 loads (8 x dwordx4 = 16 frags; consumed in Phase B)
            uint4 w2v[8];
            {
                const unsigned char* w2p = w2base + (size_t)s * 65536;
                #pragma unroll
                for (int kc = 0; kc < 4; ++kc)
                    #pragma unroll
                    for (int p = 0; p < 2; ++p)
                        w2v[kc * 2 + p] = *reinterpret_cast<const uint4*>(
                            w2p + (size_t)kc * 16384 + p * 1024);
            }

            f32x4 d0, d1;
            float dv = 0.f;
            if (it == 0) {
                dv = d0inv[s * 128 + w * 16 + lo];   // exact it0 denom reciprocal
            } else {
                // ---- Phase A (fp8): denom tiles, h and W1 operands register-resident
                f32x4 a0a = {0,0,0,0}, a0b = {0,0,0,0}, a1a = {0,0,0,0}, a1b = {0,0,0,0};
                #pragma unroll
                for (int nc = 0; nc < 16; nc += 2) {
                    a0a = __builtin_amdgcn_mfma_f32_16x16x32_fp8_fp8(hfr[0][nc],     w1buf[nc],     a0a, 0, 0, 0);
                    a1a = __builtin_amdgcn_mfma_f32_16x16x32_fp8_fp8(hfr[1][nc],     w1buf[nc],     a1a, 0, 0, 0);
                    a0b = __builtin_amdgcn_mfma_f32_16x16x32_fp8_fp8(hfr[0][nc + 1], w1buf[nc + 1], a0b, 0, 0, 0);
                    a1b = __builtin_amdgcn_mfma_f32_16x16x32_fp8_fp8(hfr[1][nc + 1], w1buf[nc + 1], a1b, 0, 0, 0);
                }
                d0 = a0a + a0b;
                d1 = a1a + a1b;
            }

            // ---- r = 16 * x * rcp(denom + eps) -> fp8 in r8_lds
            #pragma unroll
            for (int i = 0; i < 4; ++i) {
                int row0 = hi * 4 + i;
                float x0 = bf2f(x_lds[row0 * 136 + w * 16 + lo]) * 16.0f;
                float x1 = bf2f(x_lds[(16 + row0) * 136 + w * 16 + lo]) * 16.0f;
                float r0, r1;
                if (it == 0) { r0 = x0 * dv; r1 = x1 * dv; }
                else {
                    r0 = x0 * __builtin_amdgcn_rcpf(fmaf(d0[i], DSCL, 1e-20f));
                    r1 = x1 * __builtin_amdgcn_rcpf(fmaf(d1[i], DSCL, 1e-20f));
                }
                int c0 = __builtin_amdgcn_cvt_pk_fp8_f32(r0, r0, 0, false);
                int c1 = __builtin_amdgcn_cvt_pk_fp8_f32(r1, r1, 0, false);
                r8_lds[row0 * 144 + w * 16 + lo] = (unsigned char)(c0 & 0xff);
                r8_lds[(16 + row0) * 144 + w * 16 + lo] = (unsigned char)(c1 & 0xff);
            }
            LDS_BARRIER();   // barrier A (LDS-only: global prefetches stay in flight)

            // ---- Phase B 1st half (kc 0,1), fp8 MFMA
            #pragma unroll
            for (int kc = 0; kc < 2; ++kc) {
                long long ra0 = *reinterpret_cast<const long long*>(&r8_lds[lo * 144 + kc * 32 + hi * 8]);
                long long ra1 = *reinterpret_cast<const long long*>(&r8_lds[(16 + lo) * 144 + kc * 32 + hi * 8]);
                #pragma unroll
                for (int p = 0; p < 2; ++p) {
                    union { uint4 v; long long q[2]; } u;
                    u.v = w2v[kc * 2 + p];
                    #pragma unroll
                    for (int h8 = 0; h8 < 2; ++h8) {
                        int nt = p * 2 + h8;
                        tacc[0][nt] = __builtin_amdgcn_mfma_f32_16x16x32_fp8_fp8(ra0, u.q[h8], tacc[0][nt], 0, 0, 0);
                        tacc[1][nt] = __builtin_amdgcn_mfma_f32_16x16x32_fp8_fp8(ra1, u.q[h8], tacc[1][nt], 0, 0, 0);
                    }
                }
            }

            // ---- reload w1buf with W1[sn] fp8 (skip during it0 except last slot)
            if (it > 0 || s == 23) {
                const unsigned char* w1p = w1base + (size_t)sn * 65536;
                #pragma unroll
                for (int nc = 0; nc < 16; ++nc)
                    w1buf[nc] = *reinterpret_cast<const long long*>(w1p + (size_t)nc * 512);
            }

            // ---- Phase B 2nd half (kc 2,3)
            #pragma unroll
            for (int kc = 2; kc < 4; ++kc) {
                long long ra0 = *reinterpret_cast<const long long*>(&r8_lds[lo * 144 + kc * 32 + hi * 8]);
                long long ra1 = *reinterpret_cast<const long long*>(&r8_lds[(16 + lo) * 144 + kc * 32 + hi * 8]);
                #pragma unroll
                for (int p = 0; p < 2; ++p) {
                    union { uint4 v; long long q[2]; } u;
                    u.v = w2v[kc * 2 + p];
                    #pragma unroll
                    for (int h8 = 0; h8 < 2; ++h8) {
                        int nt = p * 2 + h8;
                        tacc[0][nt] = __builtin_amdgcn_mfma_f32_16x16x32_fp8_fp8(ra0, u.q[h8], tacc[0][nt], 0, 0, 0);
                        tacc[1][nt] = __builtin_amdgcn_mfma_f32_16x16x32_fp8_fp8(ra1, u.q[h8], tacc[1][nt], 0, 0, 0);
                    }
                }
            }

            // ---- stage x[s+1] (loaded a slot+ ago), rotate prefetch regs
            *reinterpret_cast<uint4*>(xdst) = xnext;
            xnext = xfut;
            LDS_BARRIER();   // barrier B
        }

        // ---- boundary: h_new = normalize(h * (1 + t*2^-16)), fp32 in regs
        float p[2][4];
        #pragma unroll
        for (int m = 0; m < 2; ++m)
            #pragma unroll
            for (int i = 0; i < 4; ++i) p[m][i] = 0.f;

        #pragma unroll
        for (int m = 0; m < 2; ++m)
            #pragma unroll
            for (int nt = 0; nt < 4; ++nt)
                #pragma unroll
                for (int i = 0; i < 4; ++i) {
                    float v = h_reg[m][nt][i] * (1.f + tacc[m][nt][i] * TS);  // EPSILON_0 = 1
                    h_reg[m][nt][i] = v;
                    p[m][i] += v;
                }
        #pragma unroll
        for (int mask = 1; mask < 16; mask <<= 1)
            #pragma unroll
            for (int m = 0; m < 2; ++m)
                #pragma unroll
                for (int i = 0; i < 4; ++i)
                    p[m][i] += __shfl_xor(p[m][i], mask, 64);
        if (lo == 0) {
            #pragma unroll
            for (int m = 0; m < 2; ++m)
                #pragma unroll
                for (int i = 0; i < 4; ++i)
                    red[w][m * 16 + hi * 4 + i] = p[m][i];
        }
        __syncthreads();
        float inv[2][4];
        #pragma unroll
        for (int m = 0; m < 2; ++m)
            #pragma unroll
            for (int i = 0; i < 4; ++i) {
                int row = m * 16 + hi * 4 + i;
                float S = 0.f;
                #pragma unroll
                for (int ww = 0; ww < 8; ++ww) S += red[ww][row];
                inv[m][i] = 1.f / (S + 1e-20f);
            }

        if (it < 4) {
            #pragma unroll
            for (int m = 0; m < 2; ++m)
                #pragma unroll
                for (int nt = 0; nt < 4; ++nt)
                    #pragma unroll
                    for (int i = 0; i < 4; ++i) {
                        int row = m * 16 + hi * 4 + i;
                        int col = w * 64 + nt * 16 + lo;
                        float hv = h_reg[m][nt][i] * inv[m][i];
                        h_reg[m][nt][i] = hv;
                        int c = __builtin_amdgcn_cvt_pk_fp8_f32(hv * 256.0f, hv * 256.0f, 0, false);
                        h8_lds[row * 528 + col] = (unsigned char)(c & 0xff);
                    }
            __syncthreads();
        } else {
            #pragma unroll
            for (int m = 0; m < 2; ++m)
                #pragma unroll
                for (int nt = 0; nt < 4; ++nt)
                    #pragma unroll
                    for (int i = 0; i < 4; ++i) {
                        int row = m * 16 + hi * 4 + i;
                        int col = w * 64 + nt * 16 + lo;
                        out[(size_t)(b0 + row) * 512 + col] = h_reg[m][nt][i] * inv[m][i];
                    }
        }
    }
}

extern "C" void kernel_launch(void* const* d_in, const int* in_sizes, int n_in,
                              void* d_out, int out_size, void* d_ws, size_t ws_size,
                              hipStream_t stream) {
    const float* x   = (const float*)d_in[0];   // [8192][3072]
    const float* wgt = (const float*)d_in[1];   // [512][3072]
    const float* h0  = (const float*)d_in[2];   // [512]
    float* out = (float*)d_out;

    // ws: X2 bf16 50,331,648 | W1 fp8 1,572,864 | W2 fp8 1,572,864 | d0inv 12,288
    unsigned short* X2 = (unsigned short*)d_ws;
    unsigned char*  W1 = (unsigned char*)((char*)d_ws + 50331648);
    unsigned char*  W2 = (unsigned char*)((char*)d_ws + 51904512);
    float* d0inv       = (float*)((char*)d_ws + 53477376);

    prep_all<<<9440, 256, 0, stream>>>(x, wgt, h0, X2, W1, W2, d0inv);
    nnmf_main<<<256, 512, 0, stream>>>(X2, W1, W2, d0inv, h0, out);
}

// Round 5
// 400.051 us; speedup vs baseline: 1.3692x; 1.1748x over previous
//
#include <hip/hip_runtime.h>

// NNMF fused: B=8192, NIN=3072, NOUT=512, 5 iterations.
// R11: MX-scaled fp8 K=128 MFMA (scale=1.0) for both phases.
//  R7-R10 evidence: VGPR pinned at 128 by the scheduler (remat of hfr LDS
//  reads) under every occupancy attribute -> restructure instead of fighting
//  the allocator. At 328 us the MFMA pipe was the largest slot component:
//  96 x 16x16x32-fp8 MFMAs/wave/slot ~ 3725 cy/SIMD of ~6300.
//  mfma_scale_f32_16x16x128_f8f6f4 (fp8/fp8, scales=2^0) runs at ~2.3x the
//  K=32 fp8 rate -> 16 MFMAs/wave/slot, pipe ~1100 cy. Phase A now streams
//  h from LDS (32B/frag, same bytes remat already paid) so the in-slot live
//  set (w1buf 32 + w2v 32 + tacc 32) genuinely fits 128 VGPRs.
//  W1/W2 repacked in prep for the K=128 fragment layout: lane l holds 32
//  CONTIGUOUS k (= one 32-elem scale block), k = (l>>4)*32 + j.
//  Numerics: identical quantization (fp8 e4m3, W x4096, h x256, r x16),
//  HW scale 2^0 exact; exact-it0 d0inv path unchanged; fp32 h master.

#define NIN 3072
#define NOUT 512

using f32x4 = __attribute__((ext_vector_type(4))) float;
using i32x8 = __attribute__((ext_vector_type(8))) int;

union frag32 { i32x8 v; uint4 q[2]; };

#define MFMA128(A, B, C) \
    __builtin_amdgcn_mfma_scale_f32_16x16x128_f8f6f4( \
        (A), (B), (C), 0, 0, 0, (int)0x7f7f7f7f, 0, (int)0x7f7f7f7f)

__device__ __forceinline__ unsigned short f2bf(float f) {
    unsigned int u = __builtin_bit_cast(unsigned int, f);
    return (unsigned short)((u + 0x7fffu + ((u >> 16) & 1u)) >> 16);  // RNE
}
__device__ __forceinline__ float bf2f(unsigned short s) {
    unsigned int u = ((unsigned int)s) << 16;
    return __builtin_bit_cast(float, u);
}

// LDS-only barrier: cross-wave deps in the slot loop are LDS-only; global
// prefetches stay in flight (consumed by issuing wave, compiler inserts vmcnt).
#define LDS_BARRIER() do {                                   \
    asm volatile("s_waitcnt lgkmcnt(0)" ::: "memory");       \
    __builtin_amdgcn_s_barrier();                            \
    asm volatile("" ::: "memory");                           \
} while (0)

// ---------------------------------------------------------------------------
// prep_all: one launch, 8672 blocks x 256 threads.
//   blocks [0,8192)     : per-row x normalize -> bf16 X2
//   blocks [8192,8576)  : W -> W2 / W1 (fp8 e4m3, x4096, K=128 frag layout)
//   blocks [8576,8672)  : d0inv[k] = 1/(sum_n h0[n]*W[n][k] + 1e-20)
// K=128 fragment layouts (lane l holds 32 contiguous elements of the
// contraction axis, k = (l>>4)*32 + j):
//   W2 (Phase B B-op): addr = ((s*32 + w*4 + nt)*64 + l)*32 + j
//     element: n = w*64 + nt*16 + (l&15), k = s*128 + (l>>4)*32 + j
//   W1 (Phase A B-op): addr = (((s*8 + w)*4 + c)*64 + l)*32 + j
//     element: kout = s*128 + w*16 + (l&15), n = c*128 + (l>>4)*32 + j
// ---------------------------------------------------------------------------
__global__ void prep_all(const float* __restrict__ x,
                         const float* __restrict__ W,
                         const float* __restrict__ h_init,
                         unsigned short* __restrict__ X2,
                         unsigned char* __restrict__ W1,
                         unsigned char* __restrict__ W2,
                         float* __restrict__ d0inv) {
    __shared__ float wsum[4];
    __shared__ float dred[8][32];
    const int bb = blockIdx.x;
    const int t  = threadIdx.x;

    if (bb < 8192) {
        // ---- x row normalize -> bf16
        const int b = bb;
        const float4* r4 = reinterpret_cast<const float4*>(x + (size_t)b * NIN);
        float s = 0.f;
        float4 v0 = r4[t], v1 = r4[t + 256], v2 = r4[t + 512];
        s = v0.x + v0.y + v0.z + v0.w + v1.x + v1.y + v1.z + v1.w + v2.x + v2.y + v2.z + v2.w;
        #pragma unroll
        for (int off = 32; off > 0; off >>= 1) s += __shfl_down(s, off, 64);
        int w = t >> 6, l = t & 63;
        if (l == 0) wsum[w] = s;
        __syncthreads();
        float inv = 1.0f / (wsum[0] + wsum[1] + wsum[2] + wsum[3] + 1e-20f);
        unsigned short* orow = X2 + (size_t)b * NIN;
        #pragma unroll
        for (int c = 0; c < 3; ++c) {
            float4 v = (c == 0) ? v0 : (c == 1) ? v1 : v2;
            ushort4 o;
            o.x = f2bf(v.x * inv); o.y = f2bf(v.y * inv);
            o.z = f2bf(v.z * inv); o.w = f2bf(v.w * inv);
            *reinterpret_cast<ushort4*>(orow + (t + c * 256) * 4) = o;
        }
    } else if (bb < 8192 + 384) {
        // ---- W quantization, K=128 frag layouts (32 B per thread)
        int tt = (bb - 8192) * 256 + t;       // 0 .. 98303
        unsigned int words[8];
        if (tt < 49152) {
            // W2: g = s*32 + w*4 + nt
            int l = tt & 63, g = tt >> 6;
            int s = g >> 5, rem = g & 31, w = rem >> 2, nt = rem & 3;
            int n = w * 64 + nt * 16 + (l & 15);
            int kbase = s * 128 + ((l >> 4) << 5);
            const float* src = W + (size_t)n * NIN + kbase;
            #pragma unroll
            for (int q = 0; q < 8; ++q) {
                float v0 = src[q * 4 + 0] * 4096.0f, v1 = src[q * 4 + 1] * 4096.0f;
                float v2 = src[q * 4 + 2] * 4096.0f, v3 = src[q * 4 + 3] * 4096.0f;
                int pk = __builtin_amdgcn_cvt_pk_fp8_f32(v0, v1, 0, false);
                pk     = __builtin_amdgcn_cvt_pk_fp8_f32(v2, v3, pk, true);
                words[q] = (unsigned int)pk;
            }
            uint4* dst = reinterpret_cast<uint4*>(W2 + (size_t)tt * 32);
            dst[0] = *reinterpret_cast<uint4*>(&words[0]);
            dst[1] = *reinterpret_cast<uint4*>(&words[4]);
        } else {
            // W1: g = (s*8 + w)*4 + c
            int u = tt - 49152;
            int l = u & 63, g = u >> 6;
            int c = g & 3, sw = g >> 2;
            int w = sw & 7, s = sw >> 3;
            int kout = s * 128 + w * 16 + (l & 15);
            int nbase = c * 128 + ((l >> 4) << 5);
            #pragma unroll
            for (int q = 0; q < 8; ++q) {
                float v0 = W[(size_t)(nbase + q * 4 + 0) * NIN + kout] * 4096.0f;
                float v1 = W[(size_t)(nbase + q * 4 + 1) * NIN + kout] * 4096.0f;
                float v2 = W[(size_t)(nbase + q * 4 + 2) * NIN + kout] * 4096.0f;
                float v3 = W[(size_t)(nbase + q * 4 + 3) * NIN + kout] * 4096.0f;
                int pk = __builtin_amdgcn_cvt_pk_fp8_f32(v0, v1, 0, false);
                pk     = __builtin_amdgcn_cvt_pk_fp8_f32(v2, v3, pk, true);
                words[q] = (unsigned int)pk;
            }
            uint4* dst = reinterpret_cast<uint4*>(W1 + (size_t)u * 32);
            dst[0] = *reinterpret_cast<uint4*>(&words[0]);
            dst[1] = *reinterpret_cast<uint4*>(&words[4]);
        }
    } else {
        // ---- d0inv: block owns 32 k-cols; thread (kid = t&31, nsub = t>>5)
        int kb = bb - 8576;                   // 0..95
        int kid = t & 31, nsub = t >> 5;      // 8 n-chunks of 64
        int k = kb * 32 + kid;
        int n0 = nsub * 64;
        float s = 0.f;
        const float* p = W + (size_t)n0 * NIN + k;
        #pragma unroll 8
        for (int n = 0; n < 64; ++n) s += h_init[n0 + n] * p[(size_t)n * NIN];
        dred[nsub][kid] = s;
        __syncthreads();
        if (t < 32) {
            float sm = 1e-20f;
            #pragma unroll
            for (int j = 0; j < 8; ++j) sm += dred[j][t];
            d0inv[kb * 32 + t] = 1.0f / sm;
        }
    }
}

// ---------------------------------------------------------------------------
// Main kernel. 256 blocks x 512 threads (8 waves), 32 rows/block, 1 block/CU.
// R7 two-barrier slot structure; MX K=128 fp8 MFMA both phases.
// ---------------------------------------------------------------------------
__global__ __launch_bounds__(512, 1) void nnmf_main(
    const unsigned short* __restrict__ X2,
    const unsigned char* __restrict__ W1,
    const unsigned char* __restrict__ W2,
    const float* __restrict__ d0inv,
    const float* __restrict__ h_init,
    float* __restrict__ out)
{
    __shared__ unsigned char  h8_lds[32 * 528];  // 16.9 KB (fp8 h, x256)
    __shared__ unsigned short x_lds[32 * 136];   // 8.7 KB
    __shared__ unsigned char  r8_lds[32 * 144];  // 4.6 KB (fp8 r, stride 144B)
    __shared__ float red[8][32];

    const int tid = threadIdx.x;
    const int w  = tid >> 6;        // wave 0..7
    const int l  = tid & 63;
    const int lo = l & 15;
    const int hi = l >> 4;          // 0..3
    const int b0 = blockIdx.x * 32;

    // fp32 h master in registers (slot-loop-dead; spillable), C-layout:
    // row = m*16 + hi*4 + i, col = w*64 + nt*16 + lo
    float h_reg[2][4][4];
    #pragma unroll
    for (int nt = 0; nt < 4; ++nt) {
        float hv = h_init[w * 64 + nt * 16 + lo];
        #pragma unroll
        for (int m = 0; m < 2; ++m)
            #pragma unroll
            for (int i = 0; i < 4; ++i)
                h_reg[m][nt][i] = hv;
    }

    // x staging: thread -> (row, 16B chunk)
    const int xrow = tid >> 4, xcc = tid & 15;
    const uint4* xg = reinterpret_cast<const uint4*>(X2 + (size_t)(b0 + xrow) * NIN + xcc * 8);
    unsigned short* xdst = &x_lds[xrow * 136 + xcc * 8];

    // W base pointers (fp8, K=128 frag layouts; 32-B aligned per lane)
    const unsigned char* w1base = W1 + (size_t)w * 8192 + (size_t)l * 32;   // +s*65536 +c*2048
    const unsigned char* w2base = W2 + ((size_t)(w * 4) * 64 + l) * 32;     // +s*65536 +nt*2048

    // prime pipeline: x[0] -> LDS, x[1] -> reg
    *reinterpret_cast<uint4*>(xdst) = xg[0];
    uint4 xnext = xg[16];
    frag32 w1buf[4];                // Phase A B-frags (valid from it0 s==23 on)
    __syncthreads();

    const float DSCL = 9.5367431640625e-07f;  // 2^-20: undo h x256 * W1 x4096
    const float TS   = 1.0f / 65536.0f;       // undo W2 x4096 and r x16 scales
    f32x4 tacc[2][4];

    for (int it = 0; it < 5; ++it) {
        #pragma unroll
        for (int m = 0; m < 2; ++m)
            #pragma unroll
            for (int nt = 0; nt < 4; ++nt)
                tacc[m][nt] = (f32x4){0.f, 0.f, 0.f, 0.f};

        for (int s = 0; s < 24; ++s) {
            const int sn  = (s + 1 == 24) ? 0 : s + 1;
            const int sn2 = (s + 2 >= 24) ? (s + 2 - 24) : s + 2;

            // ---- issue x[s+2] prefetch a full slot early
            uint4 xfut = xg[sn2 * 16];

            // ---- issue W2[s] loads (4 x 32B frags; consumed in Phase B)
            frag32 w2v[4];
            {
                const unsigned char* w2p = w2base + (size_t)s * 65536;
                #pragma unroll
                for (int nt = 0; nt < 4; ++nt) {
                    const uint4* p = reinterpret_cast<const uint4*>(w2p + nt * 2048);
                    w2v[nt].q[0] = p[0];
                    w2v[nt].q[1] = p[1];
                }
            }

            f32x4 d0, d1;
            float dv = 0.f;
            if (it == 0) {
                dv = d0inv[s * 128 + w * 16 + lo];   // exact it0 denom reciprocal
            } else {
                // ---- Phase A: denom tiles, h streamed from LDS, K=128 MFMA
                f32x4 a0 = {0,0,0,0}, a1 = {0,0,0,0};
                #pragma unroll
                for (int c = 0; c < 4; ++c) {
                    frag32 ha0, ha1;
                    const uint4* p0 = reinterpret_cast<const uint4*>(
                        &h8_lds[lo * 528 + c * 128 + hi * 32]);
                    const uint4* p1 = reinterpret_cast<const uint4*>(
                        &h8_lds[(16 + lo) * 528 + c * 128 + hi * 32]);
                    ha0.q[0] = p0[0]; ha0.q[1] = p0[1];
                    ha1.q[0] = p1[0]; ha1.q[1] = p1[1];
                    a0 = MFMA128(ha0.v, w1buf[c].v, a0);
                    a1 = MFMA128(ha1.v, w1buf[c].v, a1);
                }
                d0 = a0;
                d1 = a1;
            }

            // ---- r = 16 * x * rcp(denom + eps) -> fp8 in r8_lds
            #pragma unroll
            for (int i = 0; i < 4; ++i) {
                int row0 = hi * 4 + i;
                float x0 = bf2f(x_lds[row0 * 136 + w * 16 + lo]) * 16.0f;
                float x1 = bf2f(x_lds[(16 + row0) * 136 + w * 16 + lo]) * 16.0f;
                float r0, r1;
                if (it == 0) { r0 = x0 * dv; r1 = x1 * dv; }
                else {
                    r0 = x0 * __builtin_amdgcn_rcpf(fmaf(d0[i], DSCL, 1e-20f));
                    r1 = x1 * __builtin_amdgcn_rcpf(fmaf(d1[i], DSCL, 1e-20f));
                }
                int c0 = __builtin_amdgcn_cvt_pk_fp8_f32(r0, r0, 0, false);
                int c1 = __builtin_amdgcn_cvt_pk_fp8_f32(r1, r1, 0, false);
                r8_lds[row0 * 144 + w * 16 + lo] = (unsigned char)(c0 & 0xff);
                r8_lds[(16 + row0) * 144 + w * 16 + lo] = (unsigned char)(c1 & 0xff);
            }
            LDS_BARRIER();   // barrier A (LDS-only: global prefetches stay in flight)

            // ---- Phase B m=0: one K=128 MFMA per n-tile
            {
                frag32 ra;
                const uint4* p = reinterpret_cast<const uint4*>(&r8_lds[lo * 144 + hi * 32]);
                ra.q[0] = p[0]; ra.q[1] = p[1];
                #pragma unroll
                for (int nt = 0; nt < 4; ++nt)
                    tacc[0][nt] = MFMA128(ra.v, w2v[nt].v, tacc[0][nt]);
            }

            // ---- reload w1buf = W1[sn] (skip during it0 except last slot)
            if (it > 0 || s == 23) {
                const unsigned char* w1p = w1base + (size_t)sn * 65536;
                #pragma unroll
                for (int c = 0; c < 4; ++c) {
                    const uint4* p = reinterpret_cast<const uint4*>(w1p + c * 2048);
                    w1buf[c].q[0] = p[0];
                    w1buf[c].q[1] = p[1];
                }
            }

            // ---- Phase B m=1
            {
                frag32 ra;
                const uint4* p = reinterpret_cast<const uint4*>(&r8_lds[(16 + lo) * 144 + hi * 32]);
                ra.q[0] = p[0]; ra.q[1] = p[1];
                #pragma unroll
                for (int nt = 0; nt < 4; ++nt)
                    tacc[1][nt] = MFMA128(ra.v, w2v[nt].v, tacc[1][nt]);
            }

            // ---- stage x[s+1] (loaded a slot+ ago), rotate prefetch regs
            *reinterpret_cast<uint4*>(xdst) = xnext;
            xnext = xfut;
            LDS_BARRIER();   // barrier B
        }

        // ---- boundary: h_new = normalize(h * (1 + t*2^-16)), fp32 in regs
        float p[2][4];
        #pragma unroll
        for (int m = 0; m < 2; ++m)
            #pragma unroll
            for (int i = 0; i < 4; ++i) p[m][i] = 0.f;

        #pragma unroll
        for (int m = 0; m < 2; ++m)
            #pragma unroll
            for (int nt = 0; nt < 4; ++nt)
                #pragma unroll
                for (int i = 0; i < 4; ++i) {
                    float v = h_reg[m][nt][i] * (1.f + tacc[m][nt][i] * TS);  // EPSILON_0 = 1
                    h_reg[m][nt][i] = v;
                    p[m][i] += v;
                }
        #pragma unroll
        for (int mask = 1; mask < 16; mask <<= 1)
            #pragma unroll
            for (int m = 0; m < 2; ++m)
                #pragma unroll
                for (int i = 0; i < 4; ++i)
                    p[m][i] += __shfl_xor(p[m][i], mask, 64);
        if (lo == 0) {
            #pragma unroll
            for (int m = 0; m < 2; ++m)
                #pragma unroll
                for (int i = 0; i < 4; ++i)
                    red[w][m * 16 + hi * 4 + i] = p[m][i];
        }
        __syncthreads();
        float inv[2][4];
        #pragma unroll
        for (int m = 0; m < 2; ++m)
            #pragma unroll
            for (int i = 0; i < 4; ++i) {
                int row = m * 16 + hi * 4 + i;
                float S = 0.f;
                #pragma unroll
                for (int ww = 0; ww < 8; ++ww) S += red[ww][row];
                inv[m][i] = 1.f / (S + 1e-20f);
            }

        if (it < 4) {
            #pragma unroll
            for (int m = 0; m < 2; ++m)
                #pragma unroll
                for (int nt = 0; nt < 4; ++nt)
                    #pragma unroll
                    for (int i = 0; i < 4; ++i) {
                        int row = m * 16 + hi * 4 + i;
                        int col = w * 64 + nt * 16 + lo;
                        float hv = h_reg[m][nt][i] * inv[m][i];
                        h_reg[m][nt][i] = hv;
                        int c = __builtin_amdgcn_cvt_pk_fp8_f32(hv * 256.0f, hv * 256.0f, 0, false);
                        h8_lds[row * 528 + col] = (unsigned char)(c & 0xff);
                    }
            __syncthreads();
        } else {
            #pragma unroll
            for (int m = 0; m < 2; ++m)
                #pragma unroll
                for (int nt = 0; nt < 4; ++nt)
                    #pragma unroll
                    for (int i = 0; i < 4; ++i) {
                        int row = m * 16 + hi * 4 + i;
                        int col = w * 64 + nt * 16 + lo;
                        out[(size_t)(b0 + row) * 512 + col] = h_reg[m][nt][i] * inv[m][i];
                    }
        }
    }
}

extern "C" void kernel_launch(void* const* d_in, const int* in_sizes, int n_in,
                              void* d_out, int out_size, void* d_ws, size_t ws_size,
                              hipStream_t stream) {
    const float* x   = (const float*)d_in[0];   // [8192][3072]
    const float* wgt = (const float*)d_in[1];   // [512][3072]
    const float* h0  = (const float*)d_in[2];   // [512]
    float* out = (float*)d_out;

    // ws: X2 bf16 50,331,648 | W1 fp8 1,572,864 | W2 fp8 1,572,864 | d0inv 12,288
    unsigned short* X2 = (unsigned short*)d_ws;
    unsigned char*  W1 = (unsigned char*)((char*)d_ws + 50331648);
    unsigned char*  W2 = (unsigned char*)((char*)d_ws + 51904512);
    float* d0inv       = (float*)((char*)d_ws + 53477376);

    prep_all<<<8672, 256, 0, stream>>>(x, wgt, h0, X2, W1, W2, d0inv);
    nnmf_main<<<256, 512, 0, stream>>>(X2, W1, W2, d0inv, h0, out);
}